// Round 10
// baseline (168.075 us; speedup 1.0000x reference)
//
#include <hip/hip_runtime.h>
#include <hip/hip_fp16.h>

// LightGCN propagation: out = (f + A f + A (A f)) / 3
//   (A x)[i] = sum_{e: dst[e]==i} w[e] * x[src[e]]
// N=100000, E=1600000, D=48, fp32 in/out; fp16 internal gather operands.
//
// Pipeline:
//   prep   : FUSED features fp32->fp16 + coarse histogram (LDS-staged)
//   scan_c : exclusive scan of bucket sizes
//   partA  : tile-wise LDS-staged partition -> cw1 coarse-bucket-ordered
//   partB  : per-coarse-bucket LDS counting sort (512 thr) -> cw2 + row_ptr
//   gather : wave-per-node, 8 edge-slots x 8 feature-lanes x 6 feats,
//            unroll 3 (24 edges in flight); fp16 x-rows. Pass 2 fuses the
//            combine (fh + x1h + a)/3 entirely from fp16 streams.
// cw1 aliases x1h (cw1 dead before gather1 writes x1h).

static constexpr int D = 48;
static constexpr int CB = 256;       // nodes per coarse bucket
static constexpr int CSH = 8;        // log2(CB)
static constexpr int MAXNC = 512;    // static LDS bound on # coarse buckets
static constexpr int TILE = 4096;
static constexpr int TPB = 256;
static constexpr int EPT = TILE / TPB;  // 16 edges per thread in partA

// ---------- fused fp16 convert + coarse histogram ----------
__global__ void hc_prep(const float* __restrict__ f, __half* __restrict__ fh,
                        const int* __restrict__ dst, int* __restrict__ gcnt,
                        int n4, int E, int NC) {
    __shared__ int h[MAXNC];
    for (int i = threadIdx.x; i < NC; i += blockDim.x) h[i] = 0;
    __syncthreads();
    for (int i = blockIdx.x * blockDim.x + threadIdx.x; i < n4;
         i += gridDim.x * blockDim.x) {
        float4 v = reinterpret_cast<const float4*>(f)[i];
        reinterpret_cast<__half2*>(fh)[2 * i] = __floats2half2_rn(v.x, v.y);
        reinterpret_cast<__half2*>(fh)[2 * i + 1] = __floats2half2_rn(v.z, v.w);
    }
    for (int e = blockIdx.x * blockDim.x + threadIdx.x; e < E;
         e += gridDim.x * blockDim.x)
        atomicAdd(&h[dst[e] >> CSH], 1);
    __syncthreads();
    for (int i = threadIdx.x; i < NC; i += blockDim.x)
        if (h[i]) atomicAdd(&gcnt[i], h[i]);
}

// ---------- scan of NC (<512) bucket sizes ----------
__global__ __launch_bounds__(512) void hc_scan_c(const int* __restrict__ gcnt,
                                                 int* __restrict__ cstart,
                                                 int* __restrict__ ccur, int NC) {
    __shared__ int sm[512];
    const int t = threadIdx.x;
    int v = (t < NC) ? gcnt[t] : 0;
    sm[t] = v;
    __syncthreads();
    for (int off = 1; off < 512; off <<= 1) {
        int u = (t >= off) ? sm[t - off] : 0;
        __syncthreads();
        sm[t] += u;
        __syncthreads();
    }
    int excl = sm[t] - v;
    if (t < NC) { cstart[t] = excl; ccur[t] = excl; }
    if (t == NC) cstart[NC] = excl;  // total = E
}

// ---------- partition pass A: tile -> LDS-staged runs -> cw1 ----------
// Entry: src(17b) | (dst & 255) << 17 ; weight raw bits.
__global__ __launch_bounds__(TPB) void hc_partA(const int* __restrict__ src,
                                                const int* __restrict__ dst,
                                                const float* __restrict__ w,
                                                int* __restrict__ ccur,
                                                int2* __restrict__ cw1,
                                                int E, int NC) {
    __shared__ int2 stg[TILE];            // 32 KB
    __shared__ unsigned short sbin[TILE]; // 8 KB
    __shared__ int h[MAXNC], o[MAXNC], gb[MAXNC];
    __shared__ int sc[TPB];
    const int t = threadIdx.x;
    const int lo = blockIdx.x * TILE;
    const int cnt = min(TILE, E - lo);

    for (int i = t; i < NC; i += TPB) h[i] = 0;
    __syncthreads();

    int bn[EPT], rk[EPT];
    int2 val[EPT];
#pragma unroll
    for (int k = 0; k < EPT; ++k) {
        int idx = k * TPB + t;
        if (idx < cnt) {
            int e = lo + idx;
            int d = dst[e];
            int b = d >> CSH;
            bn[k] = b;
            rk[k] = atomicAdd(&h[b], 1);
            val[k] = make_int2(src[e] | ((d & (CB - 1)) << 17), __float_as_int(w[e]));
        } else {
            bn[k] = -1;
        }
    }
    __syncthreads();

    // exclusive scan of h[0..NC) -> o, two bins per thread
    const int i0 = 2 * t, i1 = 2 * t + 1;
    int c0 = (i0 < NC) ? h[i0] : 0;
    int c1 = (i1 < NC) ? h[i1] : 0;
    int s = c0 + c1;
    sc[t] = s;
    __syncthreads();
    for (int off = 1; off < TPB; off <<= 1) {
        int u = (t >= off) ? sc[t - off] : 0;
        __syncthreads();
        sc[t] += u;
        __syncthreads();
    }
    int ex = sc[t] - s;
    if (i0 < NC) o[i0] = ex;
    if (i1 < NC) o[i1] = ex + c0;
    __syncthreads();

    // allocate global runs (one atomic per non-empty bin)
    for (int i = t; i < NC; i += TPB)
        gb[i] = h[i] ? atomicAdd(&ccur[i], h[i]) : 0;
    __syncthreads();

    // stage entries bin-ordered in LDS
#pragma unroll
    for (int k = 0; k < EPT; ++k) {
        if (bn[k] >= 0) {
            int slot = o[bn[k]] + rk[k];
            stg[slot] = val[k];
            sbin[slot] = (unsigned short)bn[k];
        }
    }
    __syncthreads();

    // write out: consecutive threads -> consecutive addresses (full lines)
    for (int i = t; i < cnt; i += TPB) {
        int b = sbin[i];
        cw1[gb[b] + i - o[b]] = stg[i];
    }
}

// ---------- partition pass B: per-coarse-bucket node sort -> cw2 + row_ptr ----------
__global__ __launch_bounds__(512) void hc_partB(const int2* __restrict__ cw1,
                                                const int* __restrict__ cstart,
                                                int2* __restrict__ cw2,
                                                int* __restrict__ row_ptr,
                                                int N) {
    __shared__ int cnt2[CB], st2[CB], cur2[CB];
    const int cb = blockIdx.x;
    const int t = threadIdx.x;
    const int lo = cstart[cb], hi = cstart[cb + 1];

    if (t < CB) cnt2[t] = 0;
    __syncthreads();
    for (int e = lo + t; e < hi; e += 512)
        atomicAdd(&cnt2[(((unsigned)cw1[e].x) >> 17) & (CB - 1)], 1);
    __syncthreads();

    int v = (t < CB) ? cnt2[t] : 0;
    if (t < CB) st2[t] = v;
    __syncthreads();
    for (int off = 1; off < CB; off <<= 1) {
        int u = (t >= off && t < CB) ? st2[t - off] : 0;
        __syncthreads();
        if (t < CB) st2[t] += u;
        __syncthreads();
    }
    if (t < CB) {
        int excl = st2[t] - v;
        cur2[t] = excl;
        int node = cb * CB + t;
        if (node <= N) row_ptr[node] = lo + excl;
    }
    __syncthreads();

    for (int e = lo + t; e < hi; e += 512) {
        int2 p = cw1[e];
        int dl = (((unsigned)p.x) >> 17) & (CB - 1);
        int pos = lo + atomicAdd(&cur2[dl], 1);
        cw2[pos] = make_int2(p.x & 0x1FFFF, p.y);
    }
}

// ---------- gather SpMM (fp16 operand) ----------
// One wave per node; 8 edge-slots x 8 feature-lanes, 6 feats/lane (12B uint3
// load). Edge loop unrolled 3x -> 24 edges in flight. Invalid slots clamp to
// end-1 with weight 0 (branch-free).
template <bool FINAL>
__global__ __launch_bounds__(256) void hc_gather(const __half* __restrict__ xin,
                                                 const int* __restrict__ row_ptr,
                                                 const int2* __restrict__ cw,
                                                 const __half* __restrict__ fh,
                                                 const __half* __restrict__ x1h,
                                                 void* __restrict__ outv, int N) {
    const int lane = threadIdx.x & 63;
    const int node = blockIdx.x * (blockDim.x >> 6) + (threadIdx.x >> 6);
    if (node >= N) return;
    const int eslot = lane >> 3;  // 0..7
    const int fl = lane & 7;      // features [fl*6, fl*6+6)

    const int start = row_ptr[node];
    const int end = row_ptr[node + 1];

    float ac[3][6] = {};
#pragma unroll 1
    for (int eb = start; eb < end; eb += 24) {
#pragma unroll
        for (int k = 0; k < 3; ++k) {
            int e = eb + 8 * k + eslot;
            bool vld = e < end;
            int ec = vld ? e : end - 1;
            int2 p = cw[ec];
            float w = vld ? __int_as_float(p.y) : 0.f;
            const uint3 u =
                *reinterpret_cast<const uint3*>(xin + (size_t)p.x * D + fl * 6);
            float2 v0 = __half22float2(*(const __half2*)&u.x);
            float2 v1 = __half22float2(*(const __half2*)&u.y);
            float2 v2 = __half22float2(*(const __half2*)&u.z);
            ac[k][0] += w * v0.x; ac[k][1] += w * v0.y;
            ac[k][2] += w * v1.x; ac[k][3] += w * v1.y;
            ac[k][4] += w * v2.x; ac[k][5] += w * v2.y;
        }
    }

    float a[6];
#pragma unroll
    for (int j = 0; j < 6; ++j) {
        float t = ac[0][j] + ac[1][j] + ac[2][j];
        t += __shfl_xor(t, 8);
        t += __shfl_xor(t, 16);
        t += __shfl_xor(t, 32);
        a[j] = t;
    }

    if (eslot == 0) {
        const long long b = (long long)node * D + fl * 6;
        if (FINAL) {
            float* out = (float*)outv;
            constexpr float s = 1.0f / 3.0f;
#pragma unroll
            for (int j = 0; j < 6; ++j)
                out[b + j] =
                    (__half2float(fh[b + j]) + __half2float(x1h[b + j]) + a[j]) * s;
        } else {
            uint3 u;
            *(__half2*)&u.x = __floats2half2_rn(a[0], a[1]);
            *(__half2*)&u.y = __floats2half2_rn(a[2], a[3]);
            *(__half2*)&u.z = __floats2half2_rn(a[4], a[5]);
            *reinterpret_cast<uint3*>((__half*)outv + b) = u;
        }
    }
}

extern "C" void kernel_launch(void* const* d_in, const int* in_sizes, int n_in,
                              void* d_out, int out_size, void* d_ws, size_t ws_size,
                              hipStream_t stream) {
    const float* features = (const float*)d_in[0];
    const float* ew       = (const float*)d_in[1];
    const int*   ei       = (const int*)d_in[2];

    const int E = in_sizes[1];      // 1,600,000
    const int N = in_sizes[0] / D;  // 100,000

    const int* src = ei;
    const int* dst = ei + E;

    const int NC = (N + CB - 1) / CB;     // 391 coarse buckets
    const int NT = (E + TILE - 1) / TILE; // 391 tiles

    // Workspace (~36 MB). cw1 aliases x1h (cw1 dead before gather1 writes x1h).
    char*   base   = (char*)d_ws;
    int2*   cw1    = (int2*)base;                       // E entries (12.8MB)
    __half* x1h    = (__half*)base;                     // N*D fp16 (9.6MB), aliased
    int2*   cw2    = (int2*)(base + (size_t)E * 8);     // E entries (12.8MB)
    __half* fh     = (__half*)(cw2 + E);                // N*D fp16 (9.6MB)
    int*    row_ptr= (int*)(fh + (size_t)N * D);        // N+1
    int*    gcnt   = row_ptr + (N + 1);                 // NC
    int*    cstart = gcnt + NC;                         // NC+1
    int*    ccur   = cstart + (NC + 1);                 // NC

    hipMemsetAsync(gcnt, 0, (size_t)NC * sizeof(int), stream);

    const int n4 = N * D / 4;
    hc_prep<<<1024, 256, 0, stream>>>(features, fh, dst, gcnt, n4, E, NC);
    hc_scan_c<<<1, 512, 0, stream>>>(gcnt, cstart, ccur, NC);
    hc_partA<<<NT, TPB, 0, stream>>>(src, dst, ew, ccur, cw1, E, NC);
    hc_partB<<<NC, 512, 0, stream>>>(cw1, cstart, cw2, row_ptr, N);

    const int ggrid = (N + 3) / 4;  // 4 waves (nodes) per 256-thread block
    hc_gather<false><<<ggrid, 256, 0, stream>>>(fh, row_ptr, cw2,
                                                nullptr, nullptr, x1h, N);
    hc_gather<true><<<ggrid, 256, 0, stream>>>(x1h, row_ptr, cw2,
                                               fh, x1h, (float*)d_out, N);
}